// Round 9
// baseline (250.588 us; speedup 1.0000x reference)
//
#include <hip/hip_runtime.h>

#define NSTEPS 20
#define ALPHA  0.9f
#define VTH    1.0f
#define GSOMA  0.3f
#define ISCALE 0.5f

#define NOR  21
#define NORN 42
#define NLN  56
#define NPN  42
#define NKC  2000
#define NOD  34

#define TPB  256
#define KPER 8    // proven 4-wave phase2 consumer width (fallback)
#define KPW  32   // KCs per lane in the 1-wave phase2

// ============ Phase 1a: ORN + LN dynamics -> {mOrn, mLn} per step ============
// (proven: absmax 0.0, ~31 us, 4096x64 — verbatim)
__global__ __launch_bounds__(64)
void phase1a(const float* __restrict__ or_input,   // [B,21]
             const float* __restrict__ or_gains,   // [21]
             const float* __restrict__ mapping,    // [21,42]
             const float* __restrict__ orn_to_ln,  // [42,56]
             ulonglong2* __restrict__ gAB,         // [B,20] {mOrn, mLn}
             int batch)
{
    const int lane = threadIdx.x;
    const int row  = blockIdx.x;
    if (row >= batch) return;

    const int jl = lane < NLN ? lane : 0;
    float wOl[NORN];
#pragma unroll
    for (int o = 0; o < NORN; ++o) wOl[o] = orn_to_ln[o * NLN + jl];

    float spg = 0.f;
    if (lane < NOR) spg = log1pf(expf(or_gains[lane]));  // softplus

    float drive = 0.f;
    {
        const float* x = or_input + (long)row * NOR;
        const int jo = lane < NORN ? lane : 0;
#pragma unroll
        for (int i = 0; i < NOR; ++i) {
            float g = __shfl(spg, i);
            drive += x[i] * g * mapping[i * NORN + jo];
        }
        drive *= ISCALE;
    }

    float v_orn = 0.f, v_ln = 0.f;
    ulonglong2* outm = gAB + (long)row * NSTEPS;

    for (int t = 0; t < NSTEPS; ++t) {
        bool so = false;
        if (lane < NORN) {
            v_orn = ALPHA * v_orn + drive;
            so = (v_orn - VTH) > 0.f;
            if (so) v_orn = 0.f;
        }
        const unsigned long long mOrn = __ballot(so);
        const unsigned int mo_lo = (unsigned int)mOrn;
        const unsigned int mo_hi = (unsigned int)(mOrn >> 32);

        float aln = 0.f;
#pragma unroll
        for (int o = 0; o < 32; ++o) aln += (float)((mo_lo >> o) & 1u) * wOl[o];
#pragma unroll
        for (int o = 32; o < NORN; ++o) aln += (float)((mo_hi >> (o - 32)) & 1u) * wOl[o];

        bool sl = false;
        if (lane < NLN) {
            v_ln = ALPHA * v_ln + aln;
            sl = (v_ln - VTH) > 0.f;
            if (sl) v_ln = 0.f;
        }
        const unsigned long long mLn = __ballot(sl);
        if (lane == 0) outm[t] = make_ulonglong2(mOrn, mLn);
    }
}

// ============ Phase 1b: PN dynamics -> PN spike masks ============
// (proven, ~31 us, 4096x64 — verbatim)
__global__ __launch_bounds__(64)
void phase1b(const float* __restrict__ orn_to_pn,  // [42,42]
             const float* __restrict__ ln_to_pn,   // [56,42]
             const ulonglong2* __restrict__ gAB,   // [B,20]
             unsigned long long* __restrict__ gPN, // [B,20]
             int batch)
{
    const int lane = threadIdx.x;
    const int row  = blockIdx.x;
    if (row >= batch) return;

    const int jp = lane < NPN ? lane : 0;
    float wOp[NORN], wLp[NLN];
#pragma unroll
    for (int o = 0; o < NORN; ++o) wOp[o] = orn_to_pn[o * NPN + jp];
#pragma unroll
    for (int l = 0; l < NLN; ++l) wLp[l] = ln_to_pn[l * NPN + jp];

    const ulonglong2* inm = gAB + (long)row * NSTEPS;
    unsigned long long* outm = gPN + (long)row * NSTEPS;

    float v_pn = 0.f;
    ulonglong2 ab = inm[0];   // prefetch t=0

    for (int t = 0; t < NSTEPS; ++t) {
        ulonglong2 abn;
        if (t < NSTEPS - 1) abn = inm[t + 1];   // prefetch next step

        const unsigned int mo_lo = (unsigned int)ab.x;
        const unsigned int mo_hi = (unsigned int)(ab.x >> 32);
        const unsigned int ml_lo = (unsigned int)ab.y;
        const unsigned int ml_hi = (unsigned int)(ab.y >> 32);

        float apn = 0.f;
#pragma unroll
        for (int o = 0; o < 32; ++o) apn += (float)((mo_lo >> o) & 1u) * wOp[o];
#pragma unroll
        for (int o = 32; o < NORN; ++o) apn += (float)((mo_hi >> (o - 32)) & 1u) * wOp[o];

        float h = 0.f;
#pragma unroll
        for (int l = 0; l < 32; ++l) h += (float)((ml_lo >> l) & 1u) * wLp[l];
#pragma unroll
        for (int l = 32; l < NLN; ++l) h += (float)((ml_hi >> (l - 32)) & 1u) * wLp[l];

        bool sp = false;
        if (lane < NPN) {
            v_pn = ALPHA * v_pn + apn - h;
            sp = (v_pn - VTH) > 0.f;
            if (sp) v_pn = 0.f;
        }
        const unsigned long long mPn = __ballot(sp);
        if (lane == 0) outm[t] = mPn;
        ab = abn;
    }
}

// ===================== Phase 2 (1-wave, barrier-free): KC + APL + logits =====================
// One 64-lane wave per row, KPER=32. Zero barriers, zero LDS: the per-step APL
// reduce is a pure shuffle tree that replicates the PROVEN 4-wave reduction
// association EXACTLY: old thread t (KCs 8t..8t+7) = new lane t>>2, partial t&3.
// Old butterfly offsets {32,16,8,4} -> lane-offsets {8,4,2,1} on 4 partials;
// old offsets {2,1} -> (p0+p2)+(p1+p3) in-lane; old cross-wave ascending
// ((W0+W1)+W2)+W3 -> shfl broadcasts from lanes 0/16/32/48 (group g = old wave g).
// fp-add commutativity => every pairwise rounding identical => bit-exact.
// Per-KC orders (decay, adds-then-f1-fmas, soma) verbatim from the proven kernel.
// KC boundary (2000 = 250*8) handled per-8-block with clamped pointer + zero weights.
__global__ __launch_bounds__(64)
void phase2_w1(const unsigned long long* __restrict__ g_masks, // [B,20]
               const float* __restrict__ pn_to_kc,  // [42,2000]
               const float* __restrict__ kc_to_apl, // [2000,1]
               const float* __restrict__ apl_to_kc, // [1,2000]
               const float* __restrict__ dec_w,     // [2000,34]
               const float* __restrict__ dec_b,     // [34]
               float* __restrict__ out)             // [B,34]
{
    const int lane  = threadIdx.x;
    const int b     = blockIdx.x;
    const int kbase = lane * KPW;

    bool vk[4];
#pragma unroll
    for (int k = 0; k < 4; ++k) vk[k] = (kbase + k * 8) < NKC;

    float vd[KPW], va[KPW], cnt[KPW], wa2k[KPW], wk2a[KPW];
#pragma unroll
    for (int j = 0; j < KPW; ++j) { vd[j] = 0.f; va[j] = 0.f; cnt[j] = 0.f; }

    // weight load: per float4 quad q (8-block k = q>>1), clamped + zeroed like the
    // proven act-pattern (invalid blocks read offset 0, weights forced to 0).
#pragma unroll
    for (int q = 0; q < 8; ++q) {
        const int k   = q >> 1;
        const int idx = vk[k] ? (kbase + q * 4) : 0;
        const float g = vk[k] ? 1.f : 0.f;
        float4 a = *(const float4*)(apl_to_kc + idx);
        float4 c = *(const float4*)(kc_to_apl + idx);
        wa2k[q * 4 + 0] = g * a.x; wa2k[q * 4 + 1] = g * a.y;
        wa2k[q * 4 + 2] = g * a.z; wa2k[q * 4 + 3] = g * a.w;
        wk2a[q * 4 + 0] = g * c.x; wk2a[q * 4 + 1] = g * c.y;
        wk2a[q * 4 + 2] = g * c.z; wk2a[q * 4 + 3] = g * c.w;
    }

    const unsigned long long* gm = g_masks + (long)b * NSTEPS;
    unsigned long long mcur = gm[0];   // prefetch t=0
    float apl = 0.f;

    for (int t = 0; t < NSTEPS; ++t) {
        unsigned long long mnext;
        if (t < NSTEPS - 1) mnext = gm[t + 1];   // prefetch next step

        // decay (expression verbatim)
#pragma unroll
        for (int j = 0; j < KPW; ++j) vd[j] = ALPHA * vd[j] - apl * wa2k[j];

        // PN-spike gather: pairs, adds-then-f1-fmas per element (order verbatim)
        unsigned long long m = mcur;
        while (m) {
            const int p0 = __builtin_ctzll(m); m &= m - 1;
            int p1 = p0; float f1 = 0.f;
            if (m) { p1 = __builtin_ctzll(m); m &= m - 1; f1 = 1.f; }
            const float* r0 = pn_to_kc + (long)p0 * NKC;
            const float* r1 = pn_to_kc + (long)p1 * NKC;
#pragma unroll
            for (int k = 0; k < 4; ++k) {
                const int off = vk[k] ? (kbase + k * 8) : 0;
                float4 A0 = *(const float4*)(r0 + off);
                float4 A1 = *(const float4*)(r0 + off + 4);
                float4 B0 = *(const float4*)(r1 + off);
                float4 B1 = *(const float4*)(r1 + off + 4);
                vd[k*8+0] += A0.x; vd[k*8+1] += A0.y; vd[k*8+2] += A0.z; vd[k*8+3] += A0.w;
                vd[k*8+4] += A1.x; vd[k*8+5] += A1.y; vd[k*8+6] += A1.z; vd[k*8+7] += A1.w;
                vd[k*8+0] += f1 * B0.x; vd[k*8+1] += f1 * B0.y;
                vd[k*8+2] += f1 * B0.z; vd[k*8+3] += f1 * B0.w;
                vd[k*8+4] += f1 * B1.x; vd[k*8+5] += f1 * B1.y;
                vd[k*8+6] += f1 * B1.z; vd[k*8+7] += f1 * B1.w;
            }
        }

        // soma + per-old-thread APL partials (ascending j within each 8-block)
        float p[4] = {0.f, 0.f, 0.f, 0.f};
#pragma unroll
        for (int j = 0; j < KPW; ++j) {
            va[j] = ALPHA * va[j] + GSOMA * (vd[j] - va[j]);
            const bool c = (va[j] - VTH) > 0.f;
            const float s = c ? 1.f : 0.f;
            va[j] = c ? 0.f : va[j];   // proven bit-exact (R8): spiking va>VTH>0
            cnt[j] += s;
            p[j >> 3] += s * wk2a[j];
        }

        // exact replication of the proven reduction tree:
        // old offsets {32,16,8,4} == lane offsets {8,4,2,1} on the 4 partials
#pragma unroll
        for (int k = 0; k < 4; ++k) p[k] += __shfl_xor(p[k], 8, 64);
#pragma unroll
        for (int k = 0; k < 4; ++k) p[k] += __shfl_xor(p[k], 4, 64);
#pragma unroll
        for (int k = 0; k < 4; ++k) p[k] += __shfl_xor(p[k], 2, 64);
#pragma unroll
        for (int k = 0; k < 4; ++k) p[k] += __shfl_xor(p[k], 1, 64);
        // old offsets {2,1}: (p0+p2)+(p1+p3)
        const float u0 = p[0] + p[2];
        const float u1 = p[1] + p[3];
        const float W  = u0 + u1;          // old per-wave total W_g, g = lane>>4
        // old cross-wave ascending: ((W0+W1)+W2)+W3
        const float s0 = __shfl(W, 0, 64);
        const float s1 = __shfl(W, 16, 64);
        const float s2 = __shfl(W, 32, 64);
        const float s3 = __shfl(W, 48, 64);
        apl = fmaxf(((s0 + s1) + s2) + s3, 0.f);

        mcur = mnext;
    }

    // ---- decoder epilogue: same tree replication per output ----
    unsigned int rmask = 0u;
#pragma unroll
    for (int j = 0; j < KPW; ++j) {
        cnt[j] = cnt[j] / 20.0f;           // r (division exactly as proven code)
        if (vk[j >> 3] && cnt[j] != 0.f) rmask |= (1u << j);
    }

    for (int o = 0; o < NOD; ++o) {
        float p[4] = {0.f, 0.f, 0.f, 0.f};
        unsigned int mm = rmask;           // ctz ascending == ascending-j with skip
        while (mm) {
            const int j = (int)__builtin_ctz(mm); mm &= mm - 1;
            p[j >> 3] += cnt[j] * dec_w[(long)(kbase + j) * NOD + o];
        }
#pragma unroll
        for (int k = 0; k < 4; ++k) p[k] += __shfl_xor(p[k], 8, 64);
#pragma unroll
        for (int k = 0; k < 4; ++k) p[k] += __shfl_xor(p[k], 4, 64);
#pragma unroll
        for (int k = 0; k < 4; ++k) p[k] += __shfl_xor(p[k], 2, 64);
#pragma unroll
        for (int k = 0; k < 4; ++k) p[k] += __shfl_xor(p[k], 1, 64);
        const float u0 = p[0] + p[2];
        const float u1 = p[1] + p[3];
        const float W  = u0 + u1;
        const float s0 = __shfl(W, 0, 64);
        const float s1 = __shfl(W, 16, 64);
        const float s2 = __shfl(W, 32, 64);
        const float s3 = __shfl(W, 48, 64);
        const float tot = ((s0 + s1) + s2) + s3 + dec_b[o];
        if (lane == 0) out[(long)b * NOD + o] = tot;
    }
}

// ===================== Fallback: round-1 fused kernel (proven) =====================
__global__ __launch_bounds__(TPB)
void snn_fused(const float* __restrict__ or_input, const float* __restrict__ or_gains,
               const float* __restrict__ mapping, const float* __restrict__ orn_to_pn,
               const float* __restrict__ orn_to_ln, const float* __restrict__ ln_to_pn,
               const float* __restrict__ pn_to_kc, const float* __restrict__ kc_to_apl,
               const float* __restrict__ apl_to_kc, const float* __restrict__ dec_w,
               const float* __restrict__ dec_b, float* __restrict__ out)
{
    __shared__ float sW_ol[NORN * NLN];
    __shared__ float sW_op[NORN * NPN];
    __shared__ float sW_lp[NLN * NPN];
    __shared__ float sDrive[NORN];
    __shared__ float sSpg[NOR];
    __shared__ float sOrn[NORN];
    __shared__ float sLn[NLN];
    __shared__ float sApl;
    __shared__ float sRed[4];
    __shared__ float sRed2[4 * NOD];
    __shared__ unsigned long long sMask;

    const int tid = threadIdx.x;
    const int b   = blockIdx.x;

    for (int i = tid; i < NORN * NLN; i += TPB) sW_ol[i] = orn_to_ln[i];
    for (int i = tid; i < NORN * NPN; i += TPB) sW_op[i] = orn_to_pn[i];
    for (int i = tid; i < NLN * NPN;  i += TPB) sW_lp[i] = ln_to_pn[i];
    if (tid < NOR) sSpg[tid] = log1pf(expf(or_gains[tid]));
    if (tid == 0)  sApl = 0.f;
    __syncthreads();

    if (tid < NORN) {
        const float* x = or_input + (long)b * NOR;
        float d = 0.f;
        for (int i = 0; i < NOR; ++i) d += x[i] * sSpg[i] * mapping[i * NORN + tid];
        sDrive[tid] = d * ISCALE;
    }

    const int  kbase = tid * KPER;
    const bool act   = (kbase < NKC);
    float vd[KPER], va[KPER], cnt[KPER], wa2k[KPER], wk2a[KPER];
#pragma unroll
    for (int j = 0; j < KPER; ++j) {
        vd[j] = 0.f; va[j] = 0.f; cnt[j] = 0.f;
        wa2k[j] = act ? apl_to_kc[kbase + j] : 0.f;
        wk2a[j] = act ? kc_to_apl[kbase + j] : 0.f;
    }
    float v_orn = 0.f, v_ln = 0.f, v_pn = 0.f, v_pn_exc = 0.f;
    __syncthreads();

    for (int t = 0; t < NSTEPS; ++t) {
        if (tid < NORN) {
            v_orn = ALPHA * v_orn + sDrive[tid];
            float s = (v_orn - VTH) > 0.f ? 1.f : 0.f;
            v_orn *= (1.f - s);
            sOrn[tid] = s;
        }
        __syncthreads();
        if (tid < NLN) {
            float a = 0.f;
            for (int o = 0; o < NORN; ++o) a += sOrn[o] * sW_ol[o * NLN + tid];
            v_ln = ALPHA * v_ln + a;
            float s = (v_ln - VTH) > 0.f ? 1.f : 0.f;
            v_ln *= (1.f - s);
            sLn[tid] = s;
        } else if (tid >= 64 && tid < 64 + NPN) {
            const int j = tid - 64;
            float a = 0.f;
            for (int o = 0; o < NORN; ++o) a += sOrn[o] * sW_op[o * NPN + j];
            v_pn_exc = a;
        }
        __syncthreads();
        if (tid >= 64 && tid < 64 + NPN) {
            const int j = tid - 64;
            float inh = 0.f;
            for (int l = 0; l < NLN; ++l) inh += sLn[l] * sW_lp[l * NPN + j];
            v_pn = ALPHA * v_pn + v_pn_exc - inh;
            bool s = (v_pn - VTH) > 0.f;
            if (s) v_pn = 0.f;
            unsigned long long bal = __ballot(s);
            if (tid == 64) sMask = bal;
        }
        __syncthreads();
        {
            const float apl = sApl;
#pragma unroll
            for (int j = 0; j < KPER; ++j) vd[j] = ALPHA * vd[j] - apl * wa2k[j];
            unsigned long long m = sMask;
            while (m) {
                const int p = __builtin_ctzll(m);
                m &= m - 1;
                if (act) {
                    const float4* w = (const float4*)(pn_to_kc + (long)p * NKC + kbase);
                    float4 w0 = w[0], w1 = w[1];
                    vd[0] += w0.x; vd[1] += w0.y; vd[2] += w0.z; vd[3] += w0.w;
                    vd[4] += w1.x; vd[5] += w1.y; vd[6] += w1.z; vd[7] += w1.w;
                }
            }
            float aplp = 0.f;
#pragma unroll
            for (int j = 0; j < KPER; ++j) {
                va[j] = ALPHA * va[j] + GSOMA * (vd[j] - va[j]);
                float s = (va[j] - VTH) > 0.f ? 1.f : 0.f;
                va[j] *= (1.f - s);
                cnt[j] += s;
                aplp += s * wk2a[j];
            }
            for (int off = 32; off > 0; off >>= 1) aplp += __shfl_xor(aplp, off, 64);
            if ((tid & 63) == 0) sRed[tid >> 6] = aplp;
        }
        __syncthreads();
        if (tid == 0) {
            float a = sRed[0] + sRed[1] + sRed[2] + sRed[3];
            sApl = fmaxf(a, 0.f);
        }
    }

    float acc[NOD];
#pragma unroll
    for (int o = 0; o < NOD; ++o) acc[o] = 0.f;
    if (act) {
#pragma unroll
        for (int j = 0; j < KPER; ++j) {
            float r = cnt[j] / 20.0f;
            if (r != 0.f) {
                const float* wr = dec_w + (long)(kbase + j) * NOD;
#pragma unroll
                for (int o = 0; o < NOD; ++o) acc[o] += r * wr[o];
            }
        }
    }
#pragma unroll
    for (int o = 0; o < NOD; ++o) {
        float v = acc[o];
        for (int off = 32; off > 0; off >>= 1) v += __shfl_xor(v, off, 64);
        if ((tid & 63) == 0) sRed2[(tid >> 6) * NOD + o] = v;
    }
    __syncthreads();
    if (tid < NOD) {
        float v = sRed2[tid] + sRed2[NOD + tid] + sRed2[2 * NOD + tid] +
                  sRed2[3 * NOD + tid] + dec_b[tid];
        out[(long)b * NOD + tid] = v;
    }
}

extern "C" void kernel_launch(void* const* d_in, const int* in_sizes, int n_in,
                              void* d_out, int out_size, void* d_ws, size_t ws_size,
                              hipStream_t stream) {
    (void)n_in; (void)out_size;
    const float* or_input  = (const float*)d_in[0];
    const float* or_gains  = (const float*)d_in[1];
    const float* mapping   = (const float*)d_in[2];
    const float* orn_to_pn = (const float*)d_in[3];
    const float* orn_to_ln = (const float*)d_in[4];
    const float* ln_to_pn  = (const float*)d_in[5];
    const float* pn_to_kc  = (const float*)d_in[6];
    const float* kc_to_apl = (const float*)d_in[7];
    const float* apl_to_kc = (const float*)d_in[8];
    const float* dec_w     = (const float*)d_in[9];
    const float* dec_b     = (const float*)d_in[10];
    float* out = (float*)d_out;

    const int batch = in_sizes[0] / NOR;  // 4096
    const size_t needAB = (size_t)batch * NSTEPS * sizeof(ulonglong2);          // 1.31 MB
    const size_t needPN = (size_t)batch * NSTEPS * sizeof(unsigned long long);  // 0.66 MB

    if (ws_size >= needAB + needPN) {
        ulonglong2* gAB = (ulonglong2*)d_ws;
        unsigned long long* gPN = (unsigned long long*)((char*)d_ws + needAB);
        hipLaunchKernelGGL(phase1a, dim3(batch), dim3(64), 0, stream,
                           or_input, or_gains, mapping, orn_to_ln, gAB, batch);
        hipLaunchKernelGGL(phase1b, dim3(batch), dim3(64), 0, stream,
                           orn_to_pn, ln_to_pn, gAB, gPN, batch);
        hipLaunchKernelGGL(phase2_w1, dim3(batch), dim3(64), 0, stream,
                           gPN, pn_to_kc, kc_to_apl, apl_to_kc, dec_w, dec_b, out);
    } else {
        hipLaunchKernelGGL(snn_fused, dim3(batch), dim3(TPB), 0, stream,
                           or_input, or_gains, mapping, orn_to_pn, orn_to_ln,
                           ln_to_pn, pn_to_kc, kc_to_apl, apl_to_kc, dec_w, dec_b, out);
    }
}